// Round 1
// baseline (3289.342 us; speedup 1.0000x reference)
//
#include <hip/hip_runtime.h>
#include <hip/hip_bf16.h>

// Problem constants
// x: (R=64, C=256, B=4, E=768) fp32 ; query: (Q=256, B=4, QD=512)
// Wq: (768,512), Wk/Wv/Wo: (768,768), biases: (768,)
// out: (R,C,B,E) fp32
// H=12, D=64, scaling = D^-0.5/sqrt(Q) = 1/128
//
// Decomposition (verified against reference algebra):
//  xsum[r,n,e]  = sum_c x[r,c,n,e]
//  ksum[rb,e]   = xsum[rb,:] @ Wk[e,:] + 256*bk[e]        (rb = r*4+n)
//  qp[qb,e]     = (query[qb,:] @ Wq[e,:] + bq[e]) / 128   (qb = q*4+n)
//  attn[h,n,q,r]= sum_d qp[qb,h*64+d]*ksum[rb,h*64+d]
//  psum[h,n,r]  = sum_q softmax_r(attn)[h,n,q,r]
//  out[m,f]     = sum_e (x[m,:]@Wv[e,:]+bv[e]) * psum[h(e),n(m),r(m)] * Wo[f,e] + bo[f]
//                 (m = (r*256+c)*4+n -> r=m>>10, n=m&3 ; h(e)=e>>6)

__global__ __launch_bounds__(256) void xsum_kernel(const float* __restrict__ x,
                                                   float* __restrict__ xsum) {
    int gid = blockIdx.x * 256 + threadIdx.x;   // 0 .. 196607
    int e = gid % 768;
    int rb = gid / 768;                          // r*4+n
    int r = rb >> 2, n = rb & 3;
    const float* p = x + ((size_t)(r * 256) * 4 + n) * 768 + e;
    float acc = 0.f;
    #pragma unroll 8
    for (int c = 0; c < 256; ++c) acc += p[(size_t)c * 3072];
    xsum[gid] = acc;
}

// Tiled fp32 GEMM: Cout = A(MxK) @ W(NxK)^T  with per-mode epilogue.
// BM=BN=64, BK=16, 256 threads, 4x4 per thread (strided register blocking).
// MODE 0: Cf = acc + p0*bias[n]
// MODE 1: Cf = (acc + bias[n]) * p0
// MODE 2: Cb = bf16( (acc + bias[n]) * scale[((n>>6)*4 + (m&3))*64 + (m>>10)] )
// MODE 3: Cf = acc + bias[n]            (A may be bf16)
template <int MODE, typename TA>
__global__ __launch_bounds__(256) void gemm_kernel(const TA* __restrict__ A,
                                                   const float* __restrict__ W,
                                                   const float* __restrict__ bias,
                                                   const float* __restrict__ scale,
                                                   float* __restrict__ Cf,
                                                   __hip_bfloat16* __restrict__ Cb,
                                                   int M, int N, int K, float p0) {
    __shared__ float As[16][65];
    __shared__ float Ws[16][65];
    int tid = threadIdx.x;
    int tx = tid & 15, ty = tid >> 4;
    int m0 = blockIdx.y * 64, n0 = blockIdx.x * 64;
    float acc[4][4] = {};

    for (int k0 = 0; k0 < K; k0 += 16) {
        #pragma unroll
        for (int i = 0; i < 4; ++i) {
            int idx = tid + 256 * i;      // 0..1023
            int mm = idx >> 4;            // 0..63
            int kk = idx & 15;
            As[kk][mm] = (float)A[(size_t)(m0 + mm) * K + k0 + kk];
            Ws[kk][mm] = W[(size_t)(n0 + mm) * K + k0 + kk];
        }
        __syncthreads();
        #pragma unroll
        for (int kk = 0; kk < 16; ++kk) {
            float a[4], b[4];
            #pragma unroll
            for (int i = 0; i < 4; ++i) a[i] = As[kk][ty + 16 * i];
            #pragma unroll
            for (int j = 0; j < 4; ++j) b[j] = Ws[kk][tx + 16 * j];
            #pragma unroll
            for (int i = 0; i < 4; ++i)
                #pragma unroll
                for (int j = 0; j < 4; ++j) acc[i][j] += a[i] * b[j];
        }
        __syncthreads();
    }

    #pragma unroll
    for (int i = 0; i < 4; ++i) {
        int m = m0 + ty + 16 * i;
        #pragma unroll
        for (int j = 0; j < 4; ++j) {
            int n = n0 + tx + 16 * j;
            float v = acc[i][j];
            if (MODE == 0) {
                Cf[(size_t)m * N + n] = v + p0 * bias[n];
            } else if (MODE == 1) {
                Cf[(size_t)m * N + n] = (v + bias[n]) * p0;
            } else if (MODE == 2) {
                float s = scale[(((n >> 6) * 4) + (m & 3)) * 64 + (m >> 10)];
                Cb[(size_t)m * N + n] = __float2bfloat16((v + bias[n]) * s);
            } else {
                Cf[(size_t)m * N + n] = v + bias[n];
            }
        }
    }
}

// One block per (h,n): compute attn rows, softmax over r (64 lanes), and
// accumulate column-sums of probs into psum[(h*4+n)*64 + r].
__global__ __launch_bounds__(256) void attn_kernel(const float* __restrict__ qp,
                                                   const float* __restrict__ ksum,
                                                   float* __restrict__ psum) {
    int h = blockIdx.x >> 2;
    int n = blockIdx.x & 3;
    __shared__ float kd[64][65];
    __shared__ float sacc[4][64];
    int tid = threadIdx.x;

    #pragma unroll
    for (int it = 0; it < 16; ++it) {
        int idx = tid + 256 * it;   // 0..4095
        int r = idx >> 6, d = idx & 63;
        kd[r][d] = ksum[(size_t)(r * 4 + n) * 768 + h * 64 + d];
    }
    __syncthreads();

    int wave = tid >> 6, lane = tid & 63;
    float acc = 0.f;
    for (int q = wave; q < 256; q += 4) {
        float qv = qp[(size_t)(q * 4 + n) * 768 + h * 64 + lane];  // lane-indexed d
        float val = 0.f;
        #pragma unroll
        for (int d = 0; d < 64; ++d) {
            val += __shfl(qv, d) * kd[lane][d];
        }
        // softmax over the 64 lanes (r axis)
        float mx = val;
        #pragma unroll
        for (int off = 1; off < 64; off <<= 1) mx = fmaxf(mx, __shfl_xor(mx, off));
        float p = __expf(val - mx);
        float s = p;
        #pragma unroll
        for (int off = 1; off < 64; off <<= 1) s += __shfl_xor(s, off);
        acc += p / s;
    }
    sacc[wave][lane] = acc;
    __syncthreads();
    if (tid < 64) {
        float v = sacc[0][tid] + sacc[1][tid] + sacc[2][tid] + sacc[3][tid];
        psum[blockIdx.x * 64 + tid] = v;
    }
}

extern "C" void kernel_launch(void* const* d_in, const int* in_sizes, int n_in,
                              void* d_out, int out_size, void* d_ws, size_t ws_size,
                              hipStream_t stream) {
    const float* x     = (const float*)d_in[0];
    const float* query = (const float*)d_in[1];
    const float* Wq    = (const float*)d_in[2];
    const float* bq    = (const float*)d_in[3];
    const float* Wk    = (const float*)d_in[4];
    const float* bk    = (const float*)d_in[5];
    const float* Wv    = (const float*)d_in[6];
    const float* bv    = (const float*)d_in[7];
    const float* Wo    = (const float*)d_in[8];
    const float* bo    = (const float*)d_in[9];
    float* out = (float*)d_out;

    // workspace layout
    float* xsum = (float*)d_ws;              // 256*768
    float* ksum = xsum + 196608;             // 256*768
    float* qp   = ksum + 196608;             // 1024*768
    float* psum = qp + 786432;               // 12*4*64
    __hip_bfloat16* vtmp = (__hip_bfloat16*)(psum + 3072);  // 65536*768 bf16

    // 1) column-sum of x over c
    xsum_kernel<<<768, 256, 0, stream>>>(x, xsum);
    // 2) ksum = xsum @ Wk^T + 256*bk          (256 x 768 x 768)
    gemm_kernel<0, float><<<dim3(12, 4), 256, 0, stream>>>(
        xsum, Wk, bk, nullptr, ksum, nullptr, 256, 768, 768, 256.0f);
    // 3) qp = (query @ Wq^T + bq) / 128       (1024 x 768 x 512)
    gemm_kernel<1, float><<<dim3(12, 16), 256, 0, stream>>>(
        query, Wq, bq, nullptr, qp, nullptr, 1024, 768, 512, 0.0078125f);
    // 4) attention scores + softmax + prob column-sums -> psum
    attn_kernel<<<48, 256, 0, stream>>>(qp, ksum, psum);
    // 5) vtmp = bf16( (x @ Wv^T + bv) * psum )  (65536 x 768 x 768)
    gemm_kernel<2, float><<<dim3(12, 1024), 256, 0, stream>>>(
        x, Wv, bv, psum, nullptr, vtmp, 65536, 768, 768, 0.f);
    // 6) out = vtmp @ Wo^T + bo               (65536 x 768 x 768)
    gemm_kernel<3, __hip_bfloat16><<<dim3(12, 1024), 256, 0, stream>>>(
        vtmp, Wo, bo, nullptr, out, nullptr, 65536, 768, 768, 0.f);
}

// Round 3
// 835.851 us; speedup vs baseline: 3.9353x; 3.9353x over previous
//
#include <hip/hip_runtime.h>
#include <hip/hip_bf16.h>

// x: (R=64, C=256, B=4, E=768) fp32 ; query: (Q=256, B=4, QD=512)
// Wq: (768,512), Wk/Wv/Wo: (768,768), biases: (768,)  ; out: (R,C,B,E) fp32
// H=12, D=64, scaling = D^-0.5/sqrt(Q) = 1/128
//
// Decomposition:
//  xsum[rb,e]   = sum_c x[r,c,n,e]                       (rb = r*4+n)
//  ksum[rb,e]   = xsum @ Wk^T + 256*bk
//  qp[qb,e]     = (query @ Wq^T + bq) / 128              (qb = q*4+n)
//  psum[h,n,r]  = sum_q softmax_r( qp . ksum )
//  vtmp[m,e]    = bf16( (x @ Wv^T + bv) * psum[e>>6, m&3, m>>10] )
//  out[m,f]     = vtmp @ Wo^T + bo
// The two 65536x768x768 GEMMs run on MFMA (bf16 in, fp32 accum).

typedef __attribute__((ext_vector_type(8))) short bf16x8;
typedef __attribute__((ext_vector_type(4))) float f32x4;

__device__ __forceinline__ void load_lds16(const void* g, void* l) {
    __builtin_amdgcn_global_load_lds(
        (const __attribute__((address_space(1))) void*)g,
        (__attribute__((address_space(3))) void*)l, 16, 0, 0);
}

// ---- pass 1: column-sum of x over c  +  fused fp32->bf16 conversion of x ----
__global__ __launch_bounds__(256) void xsum_cvt_kernel(const float* __restrict__ x,
                                                       float* __restrict__ xsum,
                                                       __hip_bfloat16* __restrict__ xb) {
    int gid = blockIdx.x * 256 + threadIdx.x;   // 0 .. 196607
    int e = gid % 768;
    int rb = gid / 768;                          // r*4+n
    int r = rb >> 2, n = rb & 3;
    size_t base = ((size_t)(r * 256) * 4 + n) * 768 + e;
    float acc = 0.f;
    #pragma unroll 4
    for (int c = 0; c < 256; ++c) {
        float v = x[base + (size_t)c * 3072];
        acc += v;
        xb[base + (size_t)c * 3072] = __float2bfloat16(v);
    }
    xsum[gid] = acc;
}

// ---- small fp32->bf16 conversion (weights) ----
__global__ __launch_bounds__(256) void f2b_kernel(const float* __restrict__ in,
                                                  __hip_bfloat16* __restrict__ out, int n4) {
    int i = blockIdx.x * 256 + threadIdx.x;
    if (i < n4) {
        float4 v = ((const float4*)in)[i];
        out[i * 4 + 0] = __float2bfloat16(v.x);
        out[i * 4 + 1] = __float2bfloat16(v.y);
        out[i * 4 + 2] = __float2bfloat16(v.z);
        out[i * 4 + 3] = __float2bfloat16(v.w);
    }
}

// ---- small fp32 GEMM (ksum / qp): Cf = epilogue(A(MxK) @ W(NxK)^T) ----
// MODE 0: Cf = acc + p0*bias[n]     MODE 1: Cf = (acc + bias[n]) * p0
template <int MODE>
__global__ __launch_bounds__(256) void gemm_kernel(const float* __restrict__ A,
                                                   const float* __restrict__ W,
                                                   const float* __restrict__ bias,
                                                   float* __restrict__ Cf,
                                                   int M, int N, int K, float p0) {
    __shared__ float As[16][65];
    __shared__ float Ws[16][65];
    int tid = threadIdx.x;
    int tx = tid & 15, ty = tid >> 4;
    int m0 = blockIdx.y * 64, n0 = blockIdx.x * 64;
    float acc[4][4] = {};

    for (int k0 = 0; k0 < K; k0 += 16) {
        #pragma unroll
        for (int i = 0; i < 4; ++i) {
            int idx = tid + 256 * i;
            int mm = idx >> 4, kk = idx & 15;
            As[kk][mm] = A[(size_t)(m0 + mm) * K + k0 + kk];
            Ws[kk][mm] = W[(size_t)(n0 + mm) * K + k0 + kk];
        }
        __syncthreads();
        #pragma unroll
        for (int kk = 0; kk < 16; ++kk) {
            float a[4], b[4];
            #pragma unroll
            for (int i = 0; i < 4; ++i) a[i] = As[kk][ty + 16 * i];
            #pragma unroll
            for (int j = 0; j < 4; ++j) b[j] = Ws[kk][tx + 16 * j];
            #pragma unroll
            for (int i = 0; i < 4; ++i)
                #pragma unroll
                for (int j = 0; j < 4; ++j) acc[i][j] += a[i] * b[j];
        }
        __syncthreads();
    }
    #pragma unroll
    for (int i = 0; i < 4; ++i) {
        int m = m0 + ty + 16 * i;
        #pragma unroll
        for (int j = 0; j < 4; ++j) {
            int n = n0 + tx + 16 * j;
            float v = acc[i][j];
            if (MODE == 0) Cf[(size_t)m * N + n] = v + p0 * bias[n];
            else           Cf[(size_t)m * N + n] = (v + bias[n]) * p0;
        }
    }
}

// ---- attention: scores + softmax over r + column-sum of probs ----
__global__ __launch_bounds__(256) void attn_kernel(const float* __restrict__ qp,
                                                   const float* __restrict__ ksum,
                                                   float* __restrict__ psum) {
    int h = blockIdx.x >> 2;
    int n = blockIdx.x & 3;
    __shared__ float kd[64][65];
    __shared__ float sacc[4][64];
    int tid = threadIdx.x;

    #pragma unroll
    for (int it = 0; it < 16; ++it) {
        int idx = tid + 256 * it;
        int r = idx >> 6, d = idx & 63;
        kd[r][d] = ksum[(size_t)(r * 4 + n) * 768 + h * 64 + d];
    }
    __syncthreads();

    int wave = tid >> 6, lane = tid & 63;
    float acc = 0.f;
    for (int q = wave; q < 256; q += 4) {
        float qv = qp[(size_t)(q * 4 + n) * 768 + h * 64 + lane];
        float val = 0.f;
        #pragma unroll
        for (int d = 0; d < 64; ++d) val += __shfl(qv, d) * kd[lane][d];
        float mx = val;
        #pragma unroll
        for (int off = 1; off < 64; off <<= 1) mx = fmaxf(mx, __shfl_xor(mx, off));
        float p = __expf(val - mx);
        float s = p;
        #pragma unroll
        for (int off = 1; off < 64; off <<= 1) s += __shfl_xor(s, off);
        acc += p / s;
    }
    sacc[wave][lane] = acc;
    __syncthreads();
    if (tid < 64) {
        psum[blockIdx.x * 64 + tid] =
            sacc[0][tid] + sacc[1][tid] + sacc[2][tid] + sacc[3][tid];
    }
}

// ---- MFMA bf16 GEMM: C = epilogue(A(MxK) @ W(NxK)^T), m97 structure ----
// BM=BN=128, BK=32, 256 threads (4 waves, each a 64x64 quadrant of 4x4 MFMA).
// MODE 2: Cb = bf16((acc + bias[n]) * scale[((n>>6)*4 + (m&3))*64 + (m>>10)])
// MODE 3: Cf = acc + bias[n]
template <int MODE>
__global__ __launch_bounds__(256) void mfma_gemm(const ushort* __restrict__ A,
                                                 const ushort* __restrict__ W,
                                                 const float* __restrict__ bias,
                                                 const float* __restrict__ scale,
                                                 float* __restrict__ Cf,
                                                 __hip_bfloat16* __restrict__ Cb,
                                                 int M, int N, int K) {
    __shared__ short As[128 * 32];   // [m][k], 32 bf16 (64 B) per row = 4x16B chunks
    __shared__ short Bs[128 * 32];   // [n][k]
    int tid = threadIdx.x;
    int wave = tid >> 6, lane = tid & 63;
    int wr = wave >> 1, wc = wave & 1;           // 64x64 quadrant
    int m0 = blockIdx.y * 128, n0 = blockIdx.x * 128;
    int r16 = lane & 15, kg = lane >> 4;         // MFMA fragment coords

    f32x4 acc[4][4];
    #pragma unroll
    for (int i = 0; i < 4; ++i)
        #pragma unroll
        for (int j = 0; j < 4; ++j) acc[i][j] = (f32x4){0.f, 0.f, 0.f, 0.f};

    for (int k0 = 0; k0 < K; k0 += 32) {
        // stage A and B tiles: 512 chunks of 16B each (4 chunks per 32-short row)
        #pragma unroll
        for (int j = 0; j < 2; ++j) {
            int c = j * 256 + wave * 64 + lane;          // chunk 0..511
            int row = c >> 2, col8 = (c & 3) * 8;        // 4 chunks/row  [R2 bugfix]
            load_lds16(A + (size_t)(m0 + row) * K + k0 + col8,
                       &As[(j * 256 + wave * 64) * 8]);  // deposit = base + lane*16B
            load_lds16(W + (size_t)(n0 + row) * K + k0 + col8,
                       &Bs[(j * 256 + wave * 64) * 8]);
        }
        __syncthreads();   // drains vmcnt (global_load_lds) before LDS reads

        bf16x8 af[4], bv[4];
        #pragma unroll
        for (int mi = 0; mi < 4; ++mi)
            af[mi] = *(const bf16x8*)&As[(wr * 64 + mi * 16 + r16) * 32 + kg * 8];
        #pragma unroll
        for (int ni = 0; ni < 4; ++ni)
            bv[ni] = *(const bf16x8*)&Bs[(wc * 64 + ni * 16 + r16) * 32 + kg * 8];
        #pragma unroll
        for (int mi = 0; mi < 4; ++mi)
            #pragma unroll
            for (int ni = 0; ni < 4; ++ni)
                acc[mi][ni] = __builtin_amdgcn_mfma_f32_16x16x32_bf16(
                    af[mi], bv[ni], acc[mi][ni], 0, 0, 0);
        __syncthreads();   // protect LDS before next-stage overwrite
    }

    // epilogue: C/D layout col=lane&15, row=(lane>>4)*4+i
    int col = lane & 15, rbase = (lane >> 4) * 4;
    #pragma unroll
    for (int ni = 0; ni < 4; ++ni) {
        int gn = n0 + wc * 64 + ni * 16 + col;
        float bn = bias[gn];
        #pragma unroll
        for (int mi = 0; mi < 4; ++mi) {
            int gmb = m0 + wr * 64 + mi * 16 + rbase;
            #pragma unroll
            for (int i = 0; i < 4; ++i) {
                int gm = gmb + i;
                float v = acc[mi][ni][i] + bn;
                if (MODE == 2) {
                    float s = scale[(((gn >> 6) * 4) + (gm & 3)) * 64 + (gm >> 10)];
                    Cb[(size_t)gm * N + gn] = __float2bfloat16(v * s);
                } else {
                    Cf[(size_t)gm * N + gn] = v;
                }
            }
        }
    }
}

extern "C" void kernel_launch(void* const* d_in, const int* in_sizes, int n_in,
                              void* d_out, int out_size, void* d_ws, size_t ws_size,
                              hipStream_t stream) {
    const float* x     = (const float*)d_in[0];
    const float* query = (const float*)d_in[1];
    const float* Wq    = (const float*)d_in[2];
    const float* bq    = (const float*)d_in[3];
    const float* Wk    = (const float*)d_in[4];
    const float* bk    = (const float*)d_in[5];
    const float* Wv    = (const float*)d_in[6];
    const float* bv    = (const float*)d_in[7];
    const float* Wo    = (const float*)d_in[8];
    const float* bo    = (const float*)d_in[9];
    float* out = (float*)d_out;

    // workspace layout (~208 MB)
    __hip_bfloat16* xb   = (__hip_bfloat16*)d_ws;        // 65536*768
    __hip_bfloat16* vtmp = xb + 50331648;                // 65536*768
    __hip_bfloat16* Wvb  = vtmp + 50331648;              // 768*768
    __hip_bfloat16* Wob  = Wvb + 589824;                 // 768*768
    float* xsum = (float*)(Wob + 589824);                // 256*768
    float* ksum = xsum + 196608;                         // 256*768
    float* qp   = ksum + 196608;                         // 1024*768
    float* psum = qp + 786432;                           // 12*4*64

    // 1) column-sum of x over c + x -> bf16
    xsum_cvt_kernel<<<768, 256, 0, stream>>>(x, xsum, xb);
    // 1b) weights -> bf16
    f2b_kernel<<<576, 256, 0, stream>>>(Wv, Wvb, 147456);
    f2b_kernel<<<576, 256, 0, stream>>>(Wo, Wob, 147456);
    // 2) ksum = xsum @ Wk^T + 256*bk          (256 x 768 x 768)
    gemm_kernel<0><<<dim3(12, 4), 256, 0, stream>>>(xsum, Wk, bk, ksum, 256, 768, 768, 256.0f);
    // 3) qp = (query @ Wq^T + bq) / 128       (1024 x 768 x 512)
    gemm_kernel<1><<<dim3(12, 16), 256, 0, stream>>>(query, Wq, bq, qp, 1024, 768, 512, 0.0078125f);
    // 4) psum = sum_q softmax_r(qp . ksum)
    attn_kernel<<<48, 256, 0, stream>>>(qp, ksum, psum);
    // 5) vtmp = bf16((xb @ Wvb^T + bv) * psum)   MFMA  (65536 x 768 x 768)
    mfma_gemm<2><<<dim3(6, 512), 256, 0, stream>>>(
        (const ushort*)xb, (const ushort*)Wvb, bv, psum, nullptr, vtmp, 65536, 768, 768);
    // 6) out = vtmp @ Wob^T + bo                 MFMA  (65536 x 768 x 768)
    mfma_gemm<3><<<dim3(6, 512), 256, 0, stream>>>(
        (const ushort*)vtmp, (const ushort*)Wob, bo, nullptr, out, nullptr, 65536, 768, 768);
}